// Round 15
// baseline (219.200 us; speedup 1.0000x reference)
//
#include <hip/hip_runtime.h>
#include <math.h>

#define SEQ 4096
#define DM  768
#define NH  12
#define HD  64

using bf8 = __attribute__((ext_vector_type(8))) short;   // 8 bf16 = 4 VGPRs
using f4  = __attribute__((ext_vector_type(4))) float;   // 4 fp32 acc

__device__ __forceinline__ unsigned short f2bf(float f) {
    union { float f; unsigned int u; } v; v.f = f;
    unsigned int u = v.u + 0x7fffu + ((v.u >> 16) & 1u);   // RNE
    return (unsigned short)(u >> 16);
}
__device__ __forceinline__ float bf2f(unsigned short s) {
    union { unsigned int u; float f; } v; v.u = ((unsigned int)s) << 16;
    return v.f;
}

__device__ __forceinline__ f4 zero4() { f4 z = {0.f, 0.f, 0.f, 0.f}; return z; }

#define MFMA(a, b, c) __builtin_amdgcn_mfma_f32_16x16x32_bf16((a), (b), (c), 0, 0, 0)

#define QSCALE 0.18033688011112042f     // 0.125 * log2(e)
#define SHIFT  23.083120654223414f      // 16 * log2(e)
#define LDA 72                          // LDS row stride (shorts)

#define CHUNK  8                        // key-tiles per attention work item
#define NITEMS 288                      // per head: sum_{qb} ceil((qb+1)/8)

// chunk c covers key-tiles 8c..8c+7; items for chunk c: qb in [8c, 63]
__host__ __device__ __forceinline__ int chunk_off(int c) { return 64 * c - 4 * c * (c - 1); }

// ---------------------------------------------------------------------------
// Fused prep: RoPE cos/sin tables (blocks 0..511) + fp32->bf16 casts.
// ---------------------------------------------------------------------------
#define NX4 (SEQ * DM / 4)      // 786432
#define NW4 (DM * DM / 4)       // 147456
#define NCAST ((NX4 + 4 * NW4) / 256)   // 5376 blocks

__global__ __launch_bounds__(256)
void prep_kernel(const float* __restrict__ x,  const float* __restrict__ wq,
                 const float* __restrict__ wk, const float* __restrict__ wv,
                 const float* __restrict__ wo,
                 unsigned short* __restrict__ xb,  unsigned short* __restrict__ wqb,
                 unsigned short* __restrict__ wkb, unsigned short* __restrict__ wvb,
                 unsigned short* __restrict__ wob,
                 float* __restrict__ CS, float* __restrict__ SN)
{
    const int bid = blockIdx.x;
    if (bid < 512) {
        int idx = bid * 256 + threadIdx.x;         // 0 .. 131071
        int pos = idx >> 5, kf = idx & 31;
        float inv = exp2f((float)kf * (-13.287712379549449f / 32.0f));
        float sn, cs;
        sincosf((float)pos * inv, &sn, &cs);
        CS[idx] = cs; SN[idx] = sn;
        return;
    }
    int i = (bid - 512) * 256 + threadIdx.x;
    const float* src; unsigned short* dst; int j = i;
    if (j < NX4)            { src = x;  dst = xb;  }
    else { j -= NX4;
    if (j < NW4)            { src = wq; dst = wqb; }
    else { j -= NW4;
    if (j < NW4)            { src = wk; dst = wkb; }
    else { j -= NW4;
    if (j < NW4)            { src = wv; dst = wvb; }
    else { j -= NW4;          src = wo; dst = wob; } } } }
    float4 v = ((const float4*)src)[j];
    ushort4 o;
    o.x = f2bf(v.x); o.y = f2bf(v.y); o.z = f2bf(v.z); o.w = f2bf(v.w);
    ((ushort4*)dst)[j] = o;
}

// ---------------------------------------------------------------------------
// QKV projection (MFMA), 128x128 tile (N-tile = 2 heads), fused RoPE + Q
// pre-scale + V transpose.  R6/R9-proven body: plain stage->sync->MFMA.
// (R7/R8/R12 lesson: register prefetch of STAGING tiles always spills here.)
// ---------------------------------------------------------------------------
__global__ __launch_bounds__(256)
void qkv_mfma_kernel(const unsigned short* __restrict__ xb,
                     const unsigned short* __restrict__ wqb,
                     const unsigned short* __restrict__ wkb,
                     const unsigned short* __restrict__ wvb,
                     const int*            __restrict__ tokpos,
                     const float*          __restrict__ CS,
                     const float*          __restrict__ SN,
                     unsigned short* __restrict__ Qo,
                     unsigned short* __restrict__ Ko,
                     unsigned short* __restrict__ VoT)
{
    __shared__ unsigned short smem[2 * 128 * LDA];       // As | Bs (36.9 KB)
    unsigned short* As = smem;
    unsigned short* Bs = smem + 128 * LDA;
    const int tid  = threadIdx.x;
    const int wave = tid >> 6, lane = tid & 63;
    const int l15  = lane & 15, quad = lane >> 4;
    const int wm = wave & 1, wn = wave >> 1;             // 2x2 wave grid
    const int mBase = blockIdx.x * 128;
    const int hp    = blockIdx.y;                        // head pair
    const int which = blockIdx.z;
    const unsigned short* __restrict__ W = (which == 0) ? wqb : (which == 1) ? wkb : wvb;
    const int nBase = hp * 128;

    f4 acc[4][4];
    #pragma unroll
    for (int mi = 0; mi < 4; ++mi)
        #pragma unroll
        for (int ni = 0; ni < 4; ++ni) acc[mi][ni] = zero4();

    for (int k0 = 0; k0 < DM; k0 += 64) {
        #pragma unroll
        for (int t = 0; t < 4; ++t) {
            int idx = t * 256 + tid;                     // 0..1023
            int r = idx >> 3, cc = (idx & 7) * 8;
            *(uint4*)&As[r * LDA + cc] = *(const uint4*)&xb[(size_t)(mBase + r) * DM + k0 + cc];
            *(uint4*)&Bs[r * LDA + cc] = *(const uint4*)&W[(size_t)(nBase + r) * DM + k0 + cc];
        }
        __syncthreads();
        #pragma unroll
        for (int ks = 0; ks < 2; ++ks) {
            bf8 a[4], b[4];
            #pragma unroll
            for (int mi = 0; mi < 4; ++mi)
                a[mi] = *(const bf8*)&As[(wm * 64 + mi * 16 + l15) * LDA + ks * 32 + quad * 8];
            #pragma unroll
            for (int ni = 0; ni < 4; ++ni)
                b[ni] = *(const bf8*)&Bs[(wn * 64 + ni * 16 + l15) * LDA + ks * 32 + quad * 8];
            #pragma unroll
            for (int mi = 0; mi < 4; ++mi)
                #pragma unroll
                for (int ni = 0; ni < 4; ++ni)
                    acc[mi][ni] = MFMA(a[mi], b[ni], acc[mi][ni]);
        }
        __syncthreads();
    }

    if (which < 2) {
        // RoPE: head = hp*2 + wn, col = ni*16+l15; pair partner is lane^1.
        unsigned short* __restrict__ C = (which == 0) ? Qo : Ko;
        const float sc2 = (which == 0) ? QSCALE : 1.0f;
        const int head = hp * 2 + wn;
        #pragma unroll
        for (int mi = 0; mi < 4; ++mi) {
            #pragma unroll
            for (int reg = 0; reg < 4; ++reg) {
                const int rl = wm * 64 + mi * 16 + quad * 4 + reg;
                const int tb = tokpos[mBase + rl] * 32;
                #pragma unroll
                for (int ni = 0; ni < 4; ++ni) {
                    const int col = ni * 16 + l15;
                    const float cs = CS[tb + (col >> 1)];
                    const float sn = SN[tb + (col >> 1)];
                    float val = acc[mi][ni][reg];
                    float pv  = __shfl_xor(val, 1);
                    float res = (l15 & 1) ? fmaf(val, cs, pv * sn)
                                          : fmaf(val, cs, -pv * sn);
                    C[((size_t)head * SEQ + mBase + rl) * HD + col] = f2bf(res * sc2);
                }
            }
        }
    } else {
        // V: transpose 128x128 tile through LDS -> [h][64][4096].
        unsigned short* Tt = smem;                       // 128 x 136 shorts
        #pragma unroll
        for (int mi = 0; mi < 4; ++mi)
            #pragma unroll
            for (int ni = 0; ni < 4; ++ni)
                #pragma unroll
                for (int reg = 0; reg < 4; ++reg) {
                    const int m  = wm * 64 + mi * 16 + quad * 4 + reg;
                    const int cg = wn * 64 + ni * 16 + l15;
                    Tt[cg * 136 + m] = f2bf(acc[mi][ni][reg]);
                }
        __syncthreads();
        #pragma unroll
        for (int t = 0; t < 8; ++t) {
            int idx = t * 256 + tid;                     // 0..2047
            int cg = idx >> 4, c = (idx & 15) * 8;
            uint4 v = *(const uint4*)&Tt[cg * 136 + c];
            const int h2 = hp * 2 + (cg >> 6), d = cg & 63;
            *(uint4*)&VoT[((size_t)h2 * HD + d) * SEQ + mBase + c] = v;
        }
    }
}

// ---------------------------------------------------------------------------
// Flash attention, bf16 MFMA, fixed-shift softmax, split-K partials.
// ONE WAVE per block, ZERO LDS / barriers (R11 in-register quad-permute).
// R15: K-fragment cross-iteration REGISTER prefetch, budgeted to fit 256
// VGPRs by deleting the m-pipeline (sB).  kfn is issued right after m=0's
// QK MFMAs -- ~1400 cycles before its use at the next iteration top.
// Peak live: qf32 + o64 + kf32 + kfn32 + vf32 + s16 + temps ~30 = ~238.
//   permute derivation: 16*ni + 4*q' + 2*t' = 32*ks + 8*q + 2*t
//     => src_quad = ((q&1)<<1)|(t>>1), ni = (ks<<1)|(q>>1), t' = t&1
// ---------------------------------------------------------------------------
__global__ __launch_bounds__(64, 2)
void attn_mfma_kernel(const unsigned short* __restrict__ Q,
                      const unsigned short* __restrict__ K,
                      const unsigned short* __restrict__ VT,   // [h][64][4096]
                      unsigned short* __restrict__ Opart,      // [h][288][64][64]
                      float* __restrict__ Lpart)               // [h][288][64]
{
    const int lane = threadIdx.x;
    const int l15 = lane & 15, quad = lane >> 4;
    const int h  = blockIdx.y;
    const int id = blockIdx.x;                           // 0..287
    int c = 0;
    #pragma unroll
    for (int cc = 1; cc < 8; ++cc) if (id >= chunk_off(cc)) c = cc;
    const int qb  = 63 - (id - chunk_off(c));            // descending: long items first
    const int q0  = qb * 64;
    const int kt0 = CHUNK * c;
    const int kt1 = min(CHUNK * c + CHUNK - 1, qb);

    const unsigned short* __restrict__ Qh = Q  + (size_t)h * SEQ * HD;
    const unsigned short* __restrict__ Kh = K  + (size_t)h * SEQ * HD;
    const unsigned short* __restrict__ Vh = VT + (size_t)h * HD * SEQ;

    // Q as B-frag: B[k=dim][n=query]; lane l15 = query, k = ks*32+quad*8+j.
    bf8 qf[4][2];
    #pragma unroll
    for (int m = 0; m < 4; ++m)
        #pragma unroll
        for (int ks = 0; ks < 2; ++ks)
            qf[m][ks] = *(const bf8*)&Qh[(size_t)(q0 + m * 16 + l15) * HD + ks * 32 + quad * 8];

    // K A-frag double buffer; prologue loads kt0.
    bf8 kf[4][2], kfn[4][2];
    #pragma unroll
    for (int ni = 0; ni < 4; ++ni)
        #pragma unroll
        for (int ks = 0; ks < 2; ++ks)
            kf[ni][ks] = *(const bf8*)&Kh[(size_t)(kt0 * 64 + ni * 16 + l15) * HD + ks * 32 + quad * 8];

    f4 o[4][4];        // o[m][nd]: query l15, dims nd*16+quad*4+reg
    #pragma unroll
    for (int m = 0; m < 4; ++m)
        #pragma unroll
        for (int nd = 0; nd < 4; ++nd) o[m][nd] = zero4();
    float l4[4] = {0.f, 0.f, 0.f, 0.f};                  // row sums per m (query l15)

    const f4 sinit = {-SHIFT, -SHIFT, -SHIFT, -SHIFT};
    const int srcBase[2] = { (quad & 1) * 32 + l15,          // t>>1 == 0
                             (quad & 1) * 32 + 16 + l15 };   // t>>1 == 1
    const bool hiQuad = (quad >> 1) != 0;

    #pragma unroll 1
    for (int kt = kt0; kt <= kt1; ++kt) {
        // V^T as A-frag (per-iteration load; first use after QK(0)+exp(0)).
        bf8 vf[4][2];
        #pragma unroll
        for (int nd = 0; nd < 4; ++nd)
            #pragma unroll
            for (int ks = 0; ks < 2; ++ks)
                vf[nd][ks] = *(const bf8*)&Vh[(size_t)(nd * 16 + l15) * SEQ + kt * 64 + ks * 32 + quad * 8];

        const bool diag = (kt == qb);

        #pragma unroll
        for (int m = 0; m < 4; ++m) {
            // QK for this m (kf was prefetched a full iteration ago)
            f4 s[4];
            #pragma unroll
            for (int ni = 0; ni < 4; ++ni) {
                f4 t = sinit;
                t = MFMA(kf[ni][0], qf[m][0], t);
                s[ni] = MFMA(kf[ni][1], qf[m][1], t);
            }
            // issue next-iteration K prefetch as early as possible
            if (m == 0 && kt < kt1) {
                #pragma unroll
                for (int ni = 0; ni < 4; ++ni)
                    #pragma unroll
                    for (int ks = 0; ks < 2; ++ks)
                        kfn[ni][ks] = *(const bf8*)&Kh[(size_t)((kt + 1) * 64 + ni * 16 + l15) * HD + ks * 32 + quad * 8];
            }

            // exp -> (uniform) mask -> row-sum -> pack into dwords D[ni][t']
            unsigned int D[4][2];
            float lm = 0.f;
            #pragma unroll
            for (int ni = 0; ni < 4; ++ni) {
                float p[4];
                #pragma unroll
                for (int reg = 0; reg < 4; ++reg)
                    p[reg] = __builtin_amdgcn_exp2f(s[ni][reg]);
                if (diag) {
                    #pragma unroll
                    for (int reg = 0; reg < 4; ++reg)
                        if ((ni * 16 + quad * 4 + reg) > (m * 16 + l15)) p[reg] = 0.f;
                }
                lm += (p[0] + p[1]) + (p[2] + p[3]);
                union { float f; unsigned int u; } u0, u1, u2, u3;
                u0.f = p[0]; u1.f = p[1]; u2.f = p[2]; u3.f = p[3];
                D[ni][0] = __builtin_amdgcn_perm(u1.u, u0.u, 0x07060302u);
                D[ni][1] = __builtin_amdgcn_perm(u3.u, u2.u, 0x07060302u);
            }
            l4[m] += lm;

            // in-register quad-permutation: D -> PV B-frags pb0 (ks=0), pb1 (ks=1)
            union { unsigned int u[4]; bf8 v; } pb0, pb1;
            #pragma unroll
            for (int t = 0; t < 4; ++t) {
                const int srcLane = srcBase[t >> 1];   // ((q&1)*2 + (t>>1))*16 + l15
                unsigned int a0 = (unsigned int)__shfl((int)D[0][t & 1], srcLane);
                unsigned int b0 = (unsigned int)__shfl((int)D[1][t & 1], srcLane);
                pb0.u[t] = hiQuad ? b0 : a0;
                unsigned int a1 = (unsigned int)__shfl((int)D[2][t & 1], srcLane);
                unsigned int b1 = (unsigned int)__shfl((int)D[3][t & 1], srcLane);
                pb1.u[t] = hiQuad ? b1 : a1;
            }

            // O^T += V^T.P^T
            #pragma unroll
            for (int nd = 0; nd < 4; ++nd) o[m][nd] = MFMA(vf[nd][0], pb0.v, o[m][nd]);
            #pragma unroll
            for (int nd = 0; nd < 4; ++nd) o[m][nd] = MFMA(vf[nd][1], pb1.v, o[m][nd]);
        }

        if (kt < kt1) {                                // rotate in prefetched K
            #pragma unroll
            for (int ni = 0; ni < 4; ++ni)
                #pragma unroll
                for (int ks = 0; ks < 2; ++ks)
                    kf[ni][ks] = kfn[ni][ks];
        }
    }

    // epilogue: partial row sums + unnormalized O^T -> Opart[query][dim] packed 8B
    const size_t slot = (size_t)h * NITEMS + id;
    #pragma unroll
    for (int m = 0; m < 4; ++m) {
        float l = l4[m];
        l += __shfl_xor(l, 16);
        l += __shfl_xor(l, 32);
        if (quad == 0) Lpart[slot * 64 + m * 16 + l15] = l;
        #pragma unroll
        for (int nd = 0; nd < 4; ++nd) {
            uint2 d;
            d.x = ((unsigned int)f2bf(o[m][nd][1]) << 16) | f2bf(o[m][nd][0]);
            d.y = ((unsigned int)f2bf(o[m][nd][3]) << 16) | f2bf(o[m][nd][2]);
            *(uint2*)&Opart[slot * 4096 + (m * 16 + l15) * 64 + nd * 16 + quad * 4] = d;
        }
    }
}

// ---------------------------------------------------------------------------
// Reduce partials: sum <=8 chunks (uint4 = 8 bf16 at a time), normalize,
// write bf16 Ob[s][768].  One block per (q-tile, head).
// Slot mapping matches the descending-qb enumeration:
//   item id for (chunk cc, qb) = chunk_off(cc) + (63 - qb).
// ---------------------------------------------------------------------------
__global__ __launch_bounds__(256)
void attn_reduce_kernel(const unsigned short* __restrict__ Opart,
                        const float* __restrict__ Lpart,
                        unsigned short* __restrict__ Ob)
{
    const int qb = blockIdx.x, h = blockIdx.y;
    const int nc = qb / CHUNK + 1;
    const int t  = threadIdx.x;
    __shared__ float linv[64];
    if (t < 64) {
        float l = 0.f;
        for (int cc = 0; cc < nc; ++cc)
            l += Lpart[((size_t)h * NITEMS + chunk_off(cc) + 63 - qb) * 64 + t];
        linv[t] = 1.0f / l;
    }
    __syncthreads();
    #pragma unroll
    for (int uu = 0; uu < 2; ++uu) {
        const int u = uu * 256 + t;                   // 0..511
        const int row = u >> 3, ch = (u & 7) * 8;     // 8 cols per unit
        float a[8];
        #pragma unroll
        for (int e = 0; e < 8; ++e) a[e] = 0.f;
        for (int cc = 0; cc < nc; ++cc) {
            const size_t slot = (size_t)h * NITEMS + chunk_off(cc) + 63 - qb;
            uint4 v = *(const uint4*)&Opart[slot * 4096 + row * 64 + ch];
            const unsigned short* pv = (const unsigned short*)&v;
            #pragma unroll
            for (int e = 0; e < 8; ++e) a[e] += bf2f(pv[e]);
        }
        const float il = linv[row];
        ushort4 o[2];
        unsigned short* po = (unsigned short*)o;
        #pragma unroll
        for (int e = 0; e < 8; ++e) po[e] = f2bf(a[e] * il);
        *(uint4*)&Ob[(size_t)(qb * 64 + row) * DM + h * HD + ch] = *(uint4*)o;
    }
}

// ---------------------------------------------------------------------------
// Output projection (MFMA): C = O . wo^T, fp32 out.
// R14: 128x64 tile, 2-wave (128-thread) blocks -> 384 blocks.
// ---------------------------------------------------------------------------
__global__ __launch_bounds__(128)
void proj_mfma_kernel(const unsigned short* __restrict__ Ab,
                      const unsigned short* __restrict__ Wb,
                      float* __restrict__ C)
{
    __shared__ unsigned short smem[(128 + 64) * LDA];    // As(128) | Bs(64)
    unsigned short* As = smem;
    unsigned short* Bs = smem + 128 * LDA;
    const int tid  = threadIdx.x;
    const int wave = tid >> 6, lane = tid & 63;          // 2 waves
    const int l15  = lane & 15, quad = lane >> 4;
    const int mBase = blockIdx.x * 128;
    const int nBase = blockIdx.y * 64;

    f4 acc[4][4];
    #pragma unroll
    for (int mi = 0; mi < 4; ++mi)
        #pragma unroll
        for (int ni = 0; ni < 4; ++ni) acc[mi][ni] = zero4();

    for (int k0 = 0; k0 < DM; k0 += 64) {
        #pragma unroll
        for (int t = 0; t < 8; ++t) {                    // A: 1024 units
            int idx = t * 128 + tid;
            int r = idx >> 3, cc = (idx & 7) * 8;
            *(uint4*)&As[r * LDA + cc] = *(const uint4*)&Ab[(size_t)(mBase + r) * DM + k0 + cc];
        }
        #pragma unroll
        for (int t = 0; t < 4; ++t) {                    // B: 512 units
            int idx = t * 128 + tid;
            int r = idx >> 3, cc = (idx & 7) * 8;
            *(uint4*)&Bs[r * LDA + cc] = *(const uint4*)&Wb[(size_t)(nBase + r) * DM + k0 + cc];
        }
        __syncthreads();
        #pragma unroll
        for (int ks = 0; ks < 2; ++ks) {
            bf8 a[4], b[4];
            #pragma unroll
            for (int mi = 0; mi < 4; ++mi)
                a[mi] = *(const bf8*)&As[(wave * 64 + mi * 16 + l15) * LDA + ks * 32 + quad * 8];
            #pragma unroll
            for (int ni = 0; ni < 4; ++ni)
                b[ni] = *(const bf8*)&Bs[(ni * 16 + l15) * LDA + ks * 32 + quad * 8];
            #pragma unroll
            for (int mi = 0; mi < 4; ++mi)
                #pragma unroll
                for (int ni = 0; ni < 4; ++ni)
                    acc[mi][ni] = MFMA(a[mi], b[ni], acc[mi][ni]);
        }
        __syncthreads();
    }

    #pragma unroll
    for (int mi = 0; mi < 4; ++mi)
        #pragma unroll
        for (int ni = 0; ni < 4; ++ni)
            #pragma unroll
            for (int reg = 0; reg < 4; ++reg) {
                const int m = mBase + wave * 64 + mi * 16 + quad * 4 + reg;
                C[(size_t)m * DM + nBase + ni * 16 + l15] = acc[mi][ni][reg];
            }
}

// ---------------------------------------------------------------------------
extern "C" void kernel_launch(void* const* d_in, const int* in_sizes, int n_in,
                              void* d_out, int out_size, void* d_ws, size_t ws_size,
                              hipStream_t stream) {
    (void)in_sizes; (void)n_in; (void)out_size; (void)ws_size;
    const float* x      = (const float*)d_in[0];
    const float* wq     = (const float*)d_in[1];
    const float* wk     = (const float*)d_in[2];
    const float* wv     = (const float*)d_in[3];
    const float* wo     = (const float*)d_in[4];
    const int*   tokpos = (const int*)d_in[5];
    float* out = (float*)d_out;

    const size_t xN = (size_t)SEQ * DM;             // 3,145,728 shorts
    const size_t wN = (size_t)DM * DM;              //   589,824 shorts

    // persistent region
    float* CS = (float*)d_ws;                       // [4096][32]
    float* SN = CS + 4096 * 32;
    float* Lpart = SN + 4096 * 32;                  // [12][288][64] f32
    unsigned short* wob = (unsigned short*)(Lpart + (size_t)NH * NITEMS * 64);
    unsigned short* Qb  = wob + wN;                 // [h][s][64]
    unsigned short* Kb  = Qb + xN;                  // [h][s][64]
    unsigned short* VbT = Kb + xN;                  // [h][64][4096]
    unsigned short* Ob  = VbT + xN;                 // [s][768]
    // pool region: cast inputs (live until qkv) aliased with Opart (live after)
    unsigned short* pool  = Ob + xN;
    unsigned short* xb    = pool;
    unsigned short* wqb   = xb + xN;
    unsigned short* wkb   = wqb + wN;
    unsigned short* wvb   = wkb + wN;
    unsigned short* Opart = pool;                   // [12][288][64][64] = 28.3 MB

    prep_kernel<<<512 + NCAST, 256, 0, stream>>>(
        x, wq, wk, wv, wo, xb, wqb, wkb, wvb, wob, CS, SN);

    dim3 gQKV(SEQ / 128, NH / 2, 3);
    qkv_mfma_kernel<<<gQKV, 256, 0, stream>>>(xb, wqb, wkb, wvb, tokpos, CS, SN,
                                              Qb, Kb, VbT);

    dim3 gAttn(NITEMS, NH);
    attn_mfma_kernel<<<gAttn, 64, 0, stream>>>(Qb, Kb, VbT, Opart, Lpart);

    dim3 gRed(SEQ / 64, NH);
    attn_reduce_kernel<<<gRed, 256, 0, stream>>>(Opart, Lpart, Ob);

    dim3 gProj(SEQ / 128, DM / 64);
    proj_mfma_kernel<<<gProj, 128, 0, stream>>>(Ob, wob, out);
}

// Round 16
// 202.170 us; speedup vs baseline: 1.0842x; 1.0842x over previous
//
#include <hip/hip_runtime.h>
#include <math.h>

#define SEQ 4096
#define DM  768
#define NH  12
#define HD  64

using bf8 = __attribute__((ext_vector_type(8))) short;   // 8 bf16 = 4 VGPRs
using f4  = __attribute__((ext_vector_type(4))) float;   // 4 fp32 acc

__device__ __forceinline__ unsigned short f2bf(float f) {
    union { float f; unsigned int u; } v; v.f = f;
    unsigned int u = v.u + 0x7fffu + ((v.u >> 16) & 1u);   // RNE
    return (unsigned short)(u >> 16);
}
__device__ __forceinline__ float bf2f(unsigned short s) {
    union { unsigned int u; float f; } v; v.u = ((unsigned int)s) << 16;
    return v.f;
}

__device__ __forceinline__ f4 zero4() { f4 z = {0.f, 0.f, 0.f, 0.f}; return z; }

#define MFMA(a, b, c) __builtin_amdgcn_mfma_f32_16x16x32_bf16((a), (b), (c), 0, 0, 0)

#define QSCALE 0.18033688011112042f     // 0.125 * log2(e)
#define SHIFT  23.083120654223414f      // 16 * log2(e)
#define LDA 72                          // LDS row stride (shorts)

#define CHUNK  16                       // key-tiles per attention work item
#define NITEMS 160                      // per head: sum_{qb} ceil((qb+1)/16)

// chunk c covers key-tiles 16c..16c+15; items for chunk c: qb in [16c, 63]
__host__ __device__ __forceinline__ int chunk_off(int c) { return 64 * c - 8 * c * (c - 1); }

// ---------------------------------------------------------------------------
// Fused prep: RoPE cos/sin tables (blocks 0..511) + fp32->bf16 casts.
// ---------------------------------------------------------------------------
#define NX4 (SEQ * DM / 4)      // 786432
#define NW4 (DM * DM / 4)       // 147456
#define NCAST ((NX4 + 4 * NW4) / 256)   // 5376 blocks

__global__ __launch_bounds__(256)
void prep_kernel(const float* __restrict__ x,  const float* __restrict__ wq,
                 const float* __restrict__ wk, const float* __restrict__ wv,
                 const float* __restrict__ wo,
                 unsigned short* __restrict__ xb,  unsigned short* __restrict__ wqb,
                 unsigned short* __restrict__ wkb, unsigned short* __restrict__ wvb,
                 unsigned short* __restrict__ wob,
                 float* __restrict__ CS, float* __restrict__ SN)
{
    const int bid = blockIdx.x;
    if (bid < 512) {
        int idx = bid * 256 + threadIdx.x;         // 0 .. 131071
        int pos = idx >> 5, kf = idx & 31;
        float inv = exp2f((float)kf * (-13.287712379549449f / 32.0f));
        float sn, cs;
        sincosf((float)pos * inv, &sn, &cs);
        CS[idx] = cs; SN[idx] = sn;
        return;
    }
    int i = (bid - 512) * 256 + threadIdx.x;
    const float* src; unsigned short* dst; int j = i;
    if (j < NX4)            { src = x;  dst = xb;  }
    else { j -= NX4;
    if (j < NW4)            { src = wq; dst = wqb; }
    else { j -= NW4;
    if (j < NW4)            { src = wk; dst = wkb; }
    else { j -= NW4;
    if (j < NW4)            { src = wv; dst = wvb; }
    else { j -= NW4;          src = wo; dst = wob; } } } }
    float4 v = ((const float4*)src)[j];
    ushort4 o;
    o.x = f2bf(v.x); o.y = f2bf(v.y); o.z = f2bf(v.z); o.w = f2bf(v.w);
    ((ushort4*)dst)[j] = o;
}

// ---------------------------------------------------------------------------
// QKV projection (MFMA), 128x128 tile (N-tile = 2 heads), fused RoPE + Q
// pre-scale + V transpose.  R6/R9-proven body: plain stage->sync->MFMA.
// (R7/R8/R12/R15 lesson: register prefetch/double-buffer always spills.)
// ---------------------------------------------------------------------------
__global__ __launch_bounds__(256)
void qkv_mfma_kernel(const unsigned short* __restrict__ xb,
                     const unsigned short* __restrict__ wqb,
                     const unsigned short* __restrict__ wkb,
                     const unsigned short* __restrict__ wvb,
                     const int*            __restrict__ tokpos,
                     const float*          __restrict__ CS,
                     const float*          __restrict__ SN,
                     unsigned short* __restrict__ Qo,
                     unsigned short* __restrict__ Ko,
                     unsigned short* __restrict__ VoT)
{
    __shared__ unsigned short smem[2 * 128 * LDA];       // As | Bs (36.9 KB)
    unsigned short* As = smem;
    unsigned short* Bs = smem + 128 * LDA;
    const int tid  = threadIdx.x;
    const int wave = tid >> 6, lane = tid & 63;
    const int l15  = lane & 15, quad = lane >> 4;
    const int wm = wave & 1, wn = wave >> 1;             // 2x2 wave grid
    const int mBase = blockIdx.x * 128;
    const int hp    = blockIdx.y;                        // head pair
    const int which = blockIdx.z;
    const unsigned short* __restrict__ W = (which == 0) ? wqb : (which == 1) ? wkb : wvb;
    const int nBase = hp * 128;

    f4 acc[4][4];
    #pragma unroll
    for (int mi = 0; mi < 4; ++mi)
        #pragma unroll
        for (int ni = 0; ni < 4; ++ni) acc[mi][ni] = zero4();

    for (int k0 = 0; k0 < DM; k0 += 64) {
        #pragma unroll
        for (int t = 0; t < 4; ++t) {
            int idx = t * 256 + tid;                     // 0..1023
            int r = idx >> 3, cc = (idx & 7) * 8;
            *(uint4*)&As[r * LDA + cc] = *(const uint4*)&xb[(size_t)(mBase + r) * DM + k0 + cc];
            *(uint4*)&Bs[r * LDA + cc] = *(const uint4*)&W[(size_t)(nBase + r) * DM + k0 + cc];
        }
        __syncthreads();
        #pragma unroll
        for (int ks = 0; ks < 2; ++ks) {
            bf8 a[4], b[4];
            #pragma unroll
            for (int mi = 0; mi < 4; ++mi)
                a[mi] = *(const bf8*)&As[(wm * 64 + mi * 16 + l15) * LDA + ks * 32 + quad * 8];
            #pragma unroll
            for (int ni = 0; ni < 4; ++ni)
                b[ni] = *(const bf8*)&Bs[(wn * 64 + ni * 16 + l15) * LDA + ks * 32 + quad * 8];
            #pragma unroll
            for (int mi = 0; mi < 4; ++mi)
                #pragma unroll
                for (int ni = 0; ni < 4; ++ni)
                    acc[mi][ni] = MFMA(a[mi], b[ni], acc[mi][ni]);
        }
        __syncthreads();
    }

    if (which < 2) {
        // RoPE: head = hp*2 + wn, col = ni*16+l15; pair partner is lane^1.
        unsigned short* __restrict__ C = (which == 0) ? Qo : Ko;
        const float sc2 = (which == 0) ? QSCALE : 1.0f;
        const int head = hp * 2 + wn;
        #pragma unroll
        for (int mi = 0; mi < 4; ++mi) {
            #pragma unroll
            for (int reg = 0; reg < 4; ++reg) {
                const int rl = wm * 64 + mi * 16 + quad * 4 + reg;
                const int tb = tokpos[mBase + rl] * 32;
                #pragma unroll
                for (int ni = 0; ni < 4; ++ni) {
                    const int col = ni * 16 + l15;
                    const float cs = CS[tb + (col >> 1)];
                    const float sn = SN[tb + (col >> 1)];
                    float val = acc[mi][ni][reg];
                    float pv  = __shfl_xor(val, 1);
                    float res = (l15 & 1) ? fmaf(val, cs, pv * sn)
                                          : fmaf(val, cs, -pv * sn);
                    C[((size_t)head * SEQ + mBase + rl) * HD + col] = f2bf(res * sc2);
                }
            }
        }
    } else {
        // V: transpose 128x128 tile through LDS -> [h][64][4096].
        unsigned short* Tt = smem;                       // 128 x 136 shorts
        #pragma unroll
        for (int mi = 0; mi < 4; ++mi)
            #pragma unroll
            for (int ni = 0; ni < 4; ++ni)
                #pragma unroll
                for (int reg = 0; reg < 4; ++reg) {
                    const int m  = wm * 64 + mi * 16 + quad * 4 + reg;
                    const int cg = wn * 64 + ni * 16 + l15;
                    Tt[cg * 136 + m] = f2bf(acc[mi][ni][reg]);
                }
        __syncthreads();
        #pragma unroll
        for (int t = 0; t < 8; ++t) {
            int idx = t * 256 + tid;                     // 0..2047
            int cg = idx >> 4, c = (idx & 15) * 8;
            uint4 v = *(const uint4*)&Tt[cg * 136 + c];
            const int h2 = hp * 2 + (cg >> 6), d = cg & 63;
            *(uint4*)&VoT[((size_t)h2 * HD + d) * SEQ + mBase + c] = v;
        }
    }
}

// ---------------------------------------------------------------------------
// Flash attention, bf16 MFMA, fixed-shift softmax, split-K partials.
// ONE WAVE per block, ZERO LDS / barriers (R11 in-register quad-permute).
// R16: R14 body exactly (per-iteration K/V loads -- all register-prefetch
// variants spilled: R7/R8/R12/R15); CHUNK 8 -> 16: halves the per-item
// prologue/epilogue count (1920 blocks, 7.5/CU) and Opart traffic.
//   permute derivation: 16*ni + 4*q' + 2*t' = 32*ks + 8*q + 2*t
//     => src_quad = ((q&1)<<1)|(t>>1), ni = (ks<<1)|(q>>1), t' = t&1
// ---------------------------------------------------------------------------
__global__ __launch_bounds__(64, 2)
void attn_mfma_kernel(const unsigned short* __restrict__ Q,
                      const unsigned short* __restrict__ K,
                      const unsigned short* __restrict__ VT,   // [h][64][4096]
                      unsigned short* __restrict__ Opart,      // [h][160][64][64]
                      float* __restrict__ Lpart)               // [h][160][64]
{
    const int lane = threadIdx.x;
    const int l15 = lane & 15, quad = lane >> 4;
    const int h  = blockIdx.y;
    const int id = blockIdx.x;                           // 0..159
    int c = 0;
    #pragma unroll
    for (int cc = 1; cc < 4; ++cc) if (id >= chunk_off(cc)) c = cc;
    const int qb  = 63 - (id - chunk_off(c));            // descending: long items first
    const int q0  = qb * 64;
    const int kt0 = CHUNK * c;
    const int kt1 = min(CHUNK * c + CHUNK - 1, qb);

    const unsigned short* __restrict__ Qh = Q  + (size_t)h * SEQ * HD;
    const unsigned short* __restrict__ Kh = K  + (size_t)h * SEQ * HD;
    const unsigned short* __restrict__ Vh = VT + (size_t)h * HD * SEQ;

    // Q as B-frag: B[k=dim][n=query]; lane l15 = query, k = ks*32+quad*8+j.
    bf8 qf[4][2];
    #pragma unroll
    for (int m = 0; m < 4; ++m)
        #pragma unroll
        for (int ks = 0; ks < 2; ++ks)
            qf[m][ks] = *(const bf8*)&Qh[(size_t)(q0 + m * 16 + l15) * HD + ks * 32 + quad * 8];

    f4 o[4][4];        // o[m][nd]: query l15, dims nd*16+quad*4+reg
    #pragma unroll
    for (int m = 0; m < 4; ++m)
        #pragma unroll
        for (int nd = 0; nd < 4; ++nd) o[m][nd] = zero4();
    float l4[4] = {0.f, 0.f, 0.f, 0.f};                  // row sums per m (query l15)

    const f4 sinit = {-SHIFT, -SHIFT, -SHIFT, -SHIFT};
    const int srcBase[2] = { (quad & 1) * 32 + l15,          // t>>1 == 0
                             (quad & 1) * 32 + 16 + l15 };   // t>>1 == 1
    const bool hiQuad = (quad >> 1) != 0;

    #pragma unroll 1
    for (int kt = kt0; kt <= kt1; ++kt) {
        // K as A-frag: A[m=key][k=dim]; contiguous 16B.
        bf8 kf[4][2];
        #pragma unroll
        for (int ni = 0; ni < 4; ++ni)
            #pragma unroll
            for (int ks = 0; ks < 2; ++ks)
                kf[ni][ks] = *(const bf8*)&Kh[(size_t)(kt * 64 + ni * 16 + l15) * HD + ks * 32 + quad * 8];
        // V^T as A-frag: A[m=dim][k=key]; contiguous 16B.
        bf8 vf[4][2];
        #pragma unroll
        for (int nd = 0; nd < 4; ++nd)
            #pragma unroll
            for (int ks = 0; ks < 2; ++ks)
                vf[nd][ks] = *(const bf8*)&Vh[(size_t)(nd * 16 + l15) * SEQ + kt * 64 + ks * 32 + quad * 8];

        const bool diag = (kt == qb);

        // S^T for m=0
        f4 sA[4], sB[4];
        #pragma unroll
        for (int ni = 0; ni < 4; ++ni) {
            f4 t = sinit;
            t = MFMA(kf[ni][0], qf[0][0], t);
            sA[ni] = MFMA(kf[ni][1], qf[0][1], t);
        }

        #pragma unroll
        for (int m = 0; m < 4; ++m) {
            if (m < 3) {                               // QK(m+1) overlaps exp(m)
                #pragma unroll
                for (int ni = 0; ni < 4; ++ni) {
                    f4 t = sinit;
                    t = MFMA(kf[ni][0], qf[m + 1][0], t);
                    sB[ni] = MFMA(kf[ni][1], qf[m + 1][1], t);
                }
            }
            // exp -> (uniform) mask -> row-sum -> pack into dwords D[ni][t']
            unsigned int D[4][2];
            float lm = 0.f;
            #pragma unroll
            for (int ni = 0; ni < 4; ++ni) {
                float p[4];
                #pragma unroll
                for (int reg = 0; reg < 4; ++reg)
                    p[reg] = __builtin_amdgcn_exp2f(sA[ni][reg]);
                if (diag) {
                    #pragma unroll
                    for (int reg = 0; reg < 4; ++reg)
                        if ((ni * 16 + quad * 4 + reg) > (m * 16 + l15)) p[reg] = 0.f;
                }
                lm += (p[0] + p[1]) + (p[2] + p[3]);
                union { float f; unsigned int u; } u0, u1, u2, u3;
                u0.f = p[0]; u1.f = p[1]; u2.f = p[2]; u3.f = p[3];
                // one v_perm_b32 per dword: bytes [u1b3,u1b2,u0b3,u0b2]
                D[ni][0] = __builtin_amdgcn_perm(u1.u, u0.u, 0x07060302u);
                D[ni][1] = __builtin_amdgcn_perm(u3.u, u2.u, 0x07060302u);
            }
            l4[m] += lm;

            // in-register quad-permutation: D -> PV B-frags pb0 (ks=0), pb1 (ks=1)
            union { unsigned int u[4]; bf8 v; } pb0, pb1;
            #pragma unroll
            for (int t = 0; t < 4; ++t) {
                const int srcLane = srcBase[t >> 1];   // ((q&1)*2 + (t>>1))*16 + l15
                unsigned int a0 = (unsigned int)__shfl((int)D[0][t & 1], srcLane);
                unsigned int b0 = (unsigned int)__shfl((int)D[1][t & 1], srcLane);
                pb0.u[t] = hiQuad ? b0 : a0;
                unsigned int a1 = (unsigned int)__shfl((int)D[2][t & 1], srcLane);
                unsigned int b1 = (unsigned int)__shfl((int)D[3][t & 1], srcLane);
                pb1.u[t] = hiQuad ? b1 : a1;
            }

            // O^T += V^T.P^T
            #pragma unroll
            for (int nd = 0; nd < 4; ++nd) o[m][nd] = MFMA(vf[nd][0], pb0.v, o[m][nd]);
            #pragma unroll
            for (int nd = 0; nd < 4; ++nd) o[m][nd] = MFMA(vf[nd][1], pb1.v, o[m][nd]);

            if (m < 3) {
                #pragma unroll
                for (int ni = 0; ni < 4; ++ni) sA[ni] = sB[ni];
            }
        }
    }

    // epilogue: partial row sums + unnormalized O^T -> Opart[query][dim] packed 8B
    const size_t slot = (size_t)h * NITEMS + id;
    #pragma unroll
    for (int m = 0; m < 4; ++m) {
        float l = l4[m];
        l += __shfl_xor(l, 16);
        l += __shfl_xor(l, 32);
        if (quad == 0) Lpart[slot * 64 + m * 16 + l15] = l;
        #pragma unroll
        for (int nd = 0; nd < 4; ++nd) {
            uint2 d;
            d.x = ((unsigned int)f2bf(o[m][nd][1]) << 16) | f2bf(o[m][nd][0]);
            d.y = ((unsigned int)f2bf(o[m][nd][3]) << 16) | f2bf(o[m][nd][2]);
            *(uint2*)&Opart[slot * 4096 + (m * 16 + l15) * 64 + nd * 16 + quad * 4] = d;
        }
    }
}

// ---------------------------------------------------------------------------
// Reduce partials: sum <=4 chunks (uint4 = 8 bf16 at a time), normalize,
// write bf16 Ob[s][768].  One block per (q-tile, head).
// Slot mapping matches the descending-qb enumeration:
//   item id for (chunk cc, qb) = chunk_off(cc) + (63 - qb).
// ---------------------------------------------------------------------------
__global__ __launch_bounds__(256)
void attn_reduce_kernel(const unsigned short* __restrict__ Opart,
                        const float* __restrict__ Lpart,
                        unsigned short* __restrict__ Ob)
{
    const int qb = blockIdx.x, h = blockIdx.y;
    const int nc = qb / CHUNK + 1;
    const int t  = threadIdx.x;
    __shared__ float linv[64];
    if (t < 64) {
        float l = 0.f;
        for (int cc = 0; cc < nc; ++cc)
            l += Lpart[((size_t)h * NITEMS + chunk_off(cc) + 63 - qb) * 64 + t];
        linv[t] = 1.0f / l;
    }
    __syncthreads();
    #pragma unroll
    for (int uu = 0; uu < 2; ++uu) {
        const int u = uu * 256 + t;                   // 0..511
        const int row = u >> 3, ch = (u & 7) * 8;     // 8 cols per unit
        float a[8];
        #pragma unroll
        for (int e = 0; e < 8; ++e) a[e] = 0.f;
        for (int cc = 0; cc < nc; ++cc) {
            const size_t slot = (size_t)h * NITEMS + chunk_off(cc) + 63 - qb;
            uint4 v = *(const uint4*)&Opart[slot * 4096 + row * 64 + ch];
            const unsigned short* pv = (const unsigned short*)&v;
            #pragma unroll
            for (int e = 0; e < 8; ++e) a[e] += bf2f(pv[e]);
        }
        const float il = linv[row];
        ushort4 o[2];
        unsigned short* po = (unsigned short*)o;
        #pragma unroll
        for (int e = 0; e < 8; ++e) po[e] = f2bf(a[e] * il);
        *(uint4*)&Ob[(size_t)(qb * 64 + row) * DM + h * HD + ch] = *(uint4*)o;
    }
}

// ---------------------------------------------------------------------------
// Output projection (MFMA): C = O . wo^T, fp32 out.
// R14: 128x64 tile, 2-wave (128-thread) blocks -> 384 blocks.
// ---------------------------------------------------------------------------
__global__ __launch_bounds__(128)
void proj_mfma_kernel(const unsigned short* __restrict__ Ab,
                      const unsigned short* __restrict__ Wb,
                      float* __restrict__ C)
{
    __shared__ unsigned short smem[(128 + 64) * LDA];    // As(128) | Bs(64)
    unsigned short* As = smem;
    unsigned short* Bs = smem + 128 * LDA;
    const int tid  = threadIdx.x;
    const int wave = tid >> 6, lane = tid & 63;          // 2 waves
    const int l15  = lane & 15, quad = lane >> 4;
    const int mBase = blockIdx.x * 128;
    const int nBase = blockIdx.y * 64;

    f4 acc[4][4];
    #pragma unroll
    for (int mi = 0; mi < 4; ++mi)
        #pragma unroll
        for (int ni = 0; ni < 4; ++ni) acc[mi][ni] = zero4();

    for (int k0 = 0; k0 < DM; k0 += 64) {
        #pragma unroll
        for (int t = 0; t < 8; ++t) {                    // A: 1024 units
            int idx = t * 128 + tid;
            int r = idx >> 3, cc = (idx & 7) * 8;
            *(uint4*)&As[r * LDA + cc] = *(const uint4*)&Ab[(size_t)(mBase + r) * DM + k0 + cc];
        }
        #pragma unroll
        for (int t = 0; t < 4; ++t) {                    // B: 512 units
            int idx = t * 128 + tid;
            int r = idx >> 3, cc = (idx & 7) * 8;
            *(uint4*)&Bs[r * LDA + cc] = *(const uint4*)&Wb[(size_t)(nBase + r) * DM + k0 + cc];
        }
        __syncthreads();
        #pragma unroll
        for (int ks = 0; ks < 2; ++ks) {
            bf8 a[4], b[4];
            #pragma unroll
            for (int mi = 0; mi < 4; ++mi)
                a[mi] = *(const bf8*)&As[(wave * 64 + mi * 16 + l15) * LDA + ks * 32 + quad * 8];
            #pragma unroll
            for (int ni = 0; ni < 4; ++ni)
                b[ni] = *(const bf8*)&Bs[(ni * 16 + l15) * LDA + ks * 32 + quad * 8];
            #pragma unroll
            for (int mi = 0; mi < 4; ++mi)
                #pragma unroll
                for (int ni = 0; ni < 4; ++ni)
                    acc[mi][ni] = MFMA(a[mi], b[ni], acc[mi][ni]);
        }
        __syncthreads();
    }

    #pragma unroll
    for (int mi = 0; mi < 4; ++mi)
        #pragma unroll
        for (int ni = 0; ni < 4; ++ni)
            #pragma unroll
            for (int reg = 0; reg < 4; ++reg) {
                const int m = mBase + wave * 64 + mi * 16 + quad * 4 + reg;
                C[(size_t)m * DM + nBase + ni * 16 + l15] = acc[mi][ni][reg];
            }
}

// ---------------------------------------------------------------------------
extern "C" void kernel_launch(void* const* d_in, const int* in_sizes, int n_in,
                              void* d_out, int out_size, void* d_ws, size_t ws_size,
                              hipStream_t stream) {
    (void)in_sizes; (void)n_in; (void)out_size; (void)ws_size;
    const float* x      = (const float*)d_in[0];
    const float* wq     = (const float*)d_in[1];
    const float* wk     = (const float*)d_in[2];
    const float* wv     = (const float*)d_in[3];
    const float* wo     = (const float*)d_in[4];
    const int*   tokpos = (const int*)d_in[5];
    float* out = (float*)d_out;

    const size_t xN = (size_t)SEQ * DM;             // 3,145,728 shorts
    const size_t wN = (size_t)DM * DM;              //   589,824 shorts

    // persistent region
    float* CS = (float*)d_ws;                       // [4096][32]
    float* SN = CS + 4096 * 32;
    float* Lpart = SN + 4096 * 32;                  // [12][160][64] f32
    unsigned short* wob = (unsigned short*)(Lpart + (size_t)NH * NITEMS * 64);
    unsigned short* Qb  = wob + wN;                 // [h][s][64]
    unsigned short* Kb  = Qb + xN;                  // [h][s][64]
    unsigned short* VbT = Kb + xN;                  // [h][64][4096]
    unsigned short* Ob  = VbT + xN;                 // [s][768]
    // pool region: cast inputs (live until qkv) aliased with Opart (live after)
    unsigned short* pool  = Ob + xN;
    unsigned short* xb    = pool;
    unsigned short* wqb   = xb + xN;
    unsigned short* wkb   = wqb + wN;
    unsigned short* wvb   = wkb + wN;
    unsigned short* Opart = pool;                   // [12][160][64][64] = 15.7 MB

    prep_kernel<<<512 + NCAST, 256, 0, stream>>>(
        x, wq, wk, wv, wo, xb, wqb, wkb, wvb, wob, CS, SN);

    dim3 gQKV(SEQ / 128, NH / 2, 3);
    qkv_mfma_kernel<<<gQKV, 256, 0, stream>>>(xb, wqb, wkb, wvb, tokpos, CS, SN,
                                              Qb, Kb, VbT);

    dim3 gAttn(NITEMS, NH);
    attn_mfma_kernel<<<gAttn, 64, 0, stream>>>(Qb, Kb, VbT, Opart, Lpart);

    dim3 gRed(SEQ / 64, NH);
    attn_reduce_kernel<<<gRed, 256, 0, stream>>>(Opart, Lpart, Ob);

    dim3 gProj(SEQ / 128, DM / 64);
    proj_mfma_kernel<<<gProj, 128, 0, stream>>>(Ob, wob, out);
}

// Round 17
// 196.897 us; speedup vs baseline: 1.1133x; 1.0268x over previous
//
#include <hip/hip_runtime.h>
#include <math.h>

#define SEQ 4096
#define DM  768
#define NH  12
#define HD  64

using bf8 = __attribute__((ext_vector_type(8))) short;   // 8 bf16 = 4 VGPRs
using f4  = __attribute__((ext_vector_type(4))) float;   // 4 fp32 acc

__device__ __forceinline__ unsigned short f2bf(float f) {
    union { float f; unsigned int u; } v; v.f = f;
    unsigned int u = v.u + 0x7fffu + ((v.u >> 16) & 1u);   // RNE
    return (unsigned short)(u >> 16);
}
__device__ __forceinline__ float bf2f(unsigned short s) {
    union { unsigned int u; float f; } v; v.u = ((unsigned int)s) << 16;
    return v.f;
}

__device__ __forceinline__ f4 zero4() { f4 z = {0.f, 0.f, 0.f, 0.f}; return z; }

#define MFMA(a, b, c) __builtin_amdgcn_mfma_f32_16x16x32_bf16((a), (b), (c), 0, 0, 0)

#define QSCALE 0.18033688011112042f     // 0.125 * log2(e)
#define SHIFT  23.083120654223414f      // 16 * log2(e)
#define LDA 72                          // LDS row stride (shorts)

#define CHUNK  8                        // key-tiles per attention work item
#define NITEMS 288                      // per head: sum_{qb} ceil((qb+1)/8)

// chunk c covers key-tiles 8c..8c+7; items for chunk c: qb in [8c, 63]
__host__ __device__ __forceinline__ int chunk_off(int c) { return 64 * c - 4 * c * (c - 1); }

// ---------------------------------------------------------------------------
// Fused prep: RoPE cos/sin tables (blocks 0..511) + fp32->bf16 casts.
// ---------------------------------------------------------------------------
#define NX4 (SEQ * DM / 4)      // 786432
#define NW4 (DM * DM / 4)       // 147456
#define NCAST ((NX4 + 4 * NW4) / 256)   // 5376 blocks

__global__ __launch_bounds__(256)
void prep_kernel(const float* __restrict__ x,  const float* __restrict__ wq,
                 const float* __restrict__ wk, const float* __restrict__ wv,
                 const float* __restrict__ wo,
                 unsigned short* __restrict__ xb,  unsigned short* __restrict__ wqb,
                 unsigned short* __restrict__ wkb, unsigned short* __restrict__ wvb,
                 unsigned short* __restrict__ wob,
                 float* __restrict__ CS, float* __restrict__ SN)
{
    const int bid = blockIdx.x;
    if (bid < 512) {
        int idx = bid * 256 + threadIdx.x;         // 0 .. 131071
        int pos = idx >> 5, kf = idx & 31;
        float inv = exp2f((float)kf * (-13.287712379549449f / 32.0f));
        float sn, cs;
        sincosf((float)pos * inv, &sn, &cs);
        CS[idx] = cs; SN[idx] = sn;
        return;
    }
    int i = (bid - 512) * 256 + threadIdx.x;
    const float* src; unsigned short* dst; int j = i;
    if (j < NX4)            { src = x;  dst = xb;  }
    else { j -= NX4;
    if (j < NW4)            { src = wq; dst = wqb; }
    else { j -= NW4;
    if (j < NW4)            { src = wk; dst = wkb; }
    else { j -= NW4;
    if (j < NW4)            { src = wv; dst = wvb; }
    else { j -= NW4;          src = wo; dst = wob; } } } }
    float4 v = ((const float4*)src)[j];
    ushort4 o;
    o.x = f2bf(v.x); o.y = f2bf(v.y); o.z = f2bf(v.z); o.w = f2bf(v.w);
    ((ushort4*)dst)[j] = o;
}

// ---------------------------------------------------------------------------
// QKV projection (MFMA), 128x128 tile (N-tile = 2 heads), fused RoPE + Q
// pre-scale + V transpose.  R6/R9-proven body: plain stage->sync->MFMA.
// (R7/R8/R12/R15 lesson: register prefetch/double-buffer always spills.)
// ---------------------------------------------------------------------------
__global__ __launch_bounds__(256)
void qkv_mfma_kernel(const unsigned short* __restrict__ xb,
                     const unsigned short* __restrict__ wqb,
                     const unsigned short* __restrict__ wkb,
                     const unsigned short* __restrict__ wvb,
                     const int*            __restrict__ tokpos,
                     const float*          __restrict__ CS,
                     const float*          __restrict__ SN,
                     unsigned short* __restrict__ Qo,
                     unsigned short* __restrict__ Ko,
                     unsigned short* __restrict__ VoT)
{
    __shared__ unsigned short smem[2 * 128 * LDA];       // As | Bs (36.9 KB)
    unsigned short* As = smem;
    unsigned short* Bs = smem + 128 * LDA;
    const int tid  = threadIdx.x;
    const int wave = tid >> 6, lane = tid & 63;
    const int l15  = lane & 15, quad = lane >> 4;
    const int wm = wave & 1, wn = wave >> 1;             // 2x2 wave grid
    const int mBase = blockIdx.x * 128;
    const int hp    = blockIdx.y;                        // head pair
    const int which = blockIdx.z;
    const unsigned short* __restrict__ W = (which == 0) ? wqb : (which == 1) ? wkb : wvb;
    const int nBase = hp * 128;

    f4 acc[4][4];
    #pragma unroll
    for (int mi = 0; mi < 4; ++mi)
        #pragma unroll
        for (int ni = 0; ni < 4; ++ni) acc[mi][ni] = zero4();

    for (int k0 = 0; k0 < DM; k0 += 64) {
        #pragma unroll
        for (int t = 0; t < 4; ++t) {
            int idx = t * 256 + tid;                     // 0..1023
            int r = idx >> 3, cc = (idx & 7) * 8;
            *(uint4*)&As[r * LDA + cc] = *(const uint4*)&xb[(size_t)(mBase + r) * DM + k0 + cc];
            *(uint4*)&Bs[r * LDA + cc] = *(const uint4*)&W[(size_t)(nBase + r) * DM + k0 + cc];
        }
        __syncthreads();
        #pragma unroll
        for (int ks = 0; ks < 2; ++ks) {
            bf8 a[4], b[4];
            #pragma unroll
            for (int mi = 0; mi < 4; ++mi)
                a[mi] = *(const bf8*)&As[(wm * 64 + mi * 16 + l15) * LDA + ks * 32 + quad * 8];
            #pragma unroll
            for (int ni = 0; ni < 4; ++ni)
                b[ni] = *(const bf8*)&Bs[(wn * 64 + ni * 16 + l15) * LDA + ks * 32 + quad * 8];
            #pragma unroll
            for (int mi = 0; mi < 4; ++mi)
                #pragma unroll
                for (int ni = 0; ni < 4; ++ni)
                    acc[mi][ni] = MFMA(a[mi], b[ni], acc[mi][ni]);
        }
        __syncthreads();
    }

    if (which < 2) {
        // RoPE: head = hp*2 + wn, col = ni*16+l15; pair partner is lane^1.
        unsigned short* __restrict__ C = (which == 0) ? Qo : Ko;
        const float sc2 = (which == 0) ? QSCALE : 1.0f;
        const int head = hp * 2 + wn;
        #pragma unroll
        for (int mi = 0; mi < 4; ++mi) {
            #pragma unroll
            for (int reg = 0; reg < 4; ++reg) {
                const int rl = wm * 64 + mi * 16 + quad * 4 + reg;
                const int tb = tokpos[mBase + rl] * 32;
                #pragma unroll
                for (int ni = 0; ni < 4; ++ni) {
                    const int col = ni * 16 + l15;
                    const float cs = CS[tb + (col >> 1)];
                    const float sn = SN[tb + (col >> 1)];
                    float val = acc[mi][ni][reg];
                    float pv  = __shfl_xor(val, 1);
                    float res = (l15 & 1) ? fmaf(val, cs, pv * sn)
                                          : fmaf(val, cs, -pv * sn);
                    C[((size_t)head * SEQ + mBase + rl) * HD + col] = f2bf(res * sc2);
                }
            }
        }
    } else {
        // V: transpose 128x128 tile through LDS -> [h][64][4096].
        unsigned short* Tt = smem;                       // 128 x 136 shorts
        #pragma unroll
        for (int mi = 0; mi < 4; ++mi)
            #pragma unroll
            for (int ni = 0; ni < 4; ++ni)
                #pragma unroll
                for (int reg = 0; reg < 4; ++reg) {
                    const int m  = wm * 64 + mi * 16 + quad * 4 + reg;
                    const int cg = wn * 64 + ni * 16 + l15;
                    Tt[cg * 136 + m] = f2bf(acc[mi][ni][reg]);
                }
        __syncthreads();
        #pragma unroll
        for (int t = 0; t < 8; ++t) {
            int idx = t * 256 + tid;                     // 0..2047
            int cg = idx >> 4, c = (idx & 15) * 8;
            uint4 v = *(const uint4*)&Tt[cg * 136 + c];
            const int h2 = hp * 2 + (cg >> 6), d = cg & 63;
            *(uint4*)&VoT[((size_t)h2 * HD + d) * SEQ + mBase + c] = v;
        }
    }
}

// ---------------------------------------------------------------------------
// Flash attention, bf16 MFMA, fixed-shift softmax, split-K partials.
// ONE WAVE per block, ZERO LDS / barriers (R11 in-register quad-permute).
// Best-measured config (R14): CHUNK=8, v_perm pack, descending-qb order.
// Per-iteration K/V loads (all register-prefetch variants spilled:
// R7/R8/R12/R15 -- compiler caps this kernel at 128 VGPRs).
//   permute derivation: 16*ni + 4*q' + 2*t' = 32*ks + 8*q + 2*t
//     => src_quad = ((q&1)<<1)|(t>>1), ni = (ks<<1)|(q>>1), t' = t&1
// ---------------------------------------------------------------------------
__global__ __launch_bounds__(64, 2)
void attn_mfma_kernel(const unsigned short* __restrict__ Q,
                      const unsigned short* __restrict__ K,
                      const unsigned short* __restrict__ VT,   // [h][64][4096]
                      unsigned short* __restrict__ Opart,      // [h][288][64][64]
                      float* __restrict__ Lpart)               // [h][288][64]
{
    const int lane = threadIdx.x;
    const int l15 = lane & 15, quad = lane >> 4;
    const int h  = blockIdx.y;
    const int id = blockIdx.x;                           // 0..287
    int c = 0;
    #pragma unroll
    for (int cc = 1; cc < 8; ++cc) if (id >= chunk_off(cc)) c = cc;
    const int qb  = 63 - (id - chunk_off(c));            // descending: long items first
    const int q0  = qb * 64;
    const int kt0 = CHUNK * c;
    const int kt1 = min(CHUNK * c + CHUNK - 1, qb);

    const unsigned short* __restrict__ Qh = Q  + (size_t)h * SEQ * HD;
    const unsigned short* __restrict__ Kh = K  + (size_t)h * SEQ * HD;
    const unsigned short* __restrict__ Vh = VT + (size_t)h * HD * SEQ;

    // Q as B-frag: B[k=dim][n=query]; lane l15 = query, k = ks*32+quad*8+j.
    bf8 qf[4][2];
    #pragma unroll
    for (int m = 0; m < 4; ++m)
        #pragma unroll
        for (int ks = 0; ks < 2; ++ks)
            qf[m][ks] = *(const bf8*)&Qh[(size_t)(q0 + m * 16 + l15) * HD + ks * 32 + quad * 8];

    f4 o[4][4];        // o[m][nd]: query l15, dims nd*16+quad*4+reg
    #pragma unroll
    for (int m = 0; m < 4; ++m)
        #pragma unroll
        for (int nd = 0; nd < 4; ++nd) o[m][nd] = zero4();
    float l4[4] = {0.f, 0.f, 0.f, 0.f};                  // row sums per m (query l15)

    const f4 sinit = {-SHIFT, -SHIFT, -SHIFT, -SHIFT};
    const int srcBase[2] = { (quad & 1) * 32 + l15,          // t>>1 == 0
                             (quad & 1) * 32 + 16 + l15 };   // t>>1 == 1
    const bool hiQuad = (quad >> 1) != 0;

    #pragma unroll 1
    for (int kt = kt0; kt <= kt1; ++kt) {
        // K as A-frag: A[m=key][k=dim]; contiguous 16B.
        bf8 kf[4][2];
        #pragma unroll
        for (int ni = 0; ni < 4; ++ni)
            #pragma unroll
            for (int ks = 0; ks < 2; ++ks)
                kf[ni][ks] = *(const bf8*)&Kh[(size_t)(kt * 64 + ni * 16 + l15) * HD + ks * 32 + quad * 8];
        // V^T as A-frag: A[m=dim][k=key]; contiguous 16B.
        bf8 vf[4][2];
        #pragma unroll
        for (int nd = 0; nd < 4; ++nd)
            #pragma unroll
            for (int ks = 0; ks < 2; ++ks)
                vf[nd][ks] = *(const bf8*)&Vh[(size_t)(nd * 16 + l15) * SEQ + kt * 64 + ks * 32 + quad * 8];

        const bool diag = (kt == qb);

        // S^T for m=0
        f4 sA[4], sB[4];
        #pragma unroll
        for (int ni = 0; ni < 4; ++ni) {
            f4 t = sinit;
            t = MFMA(kf[ni][0], qf[0][0], t);
            sA[ni] = MFMA(kf[ni][1], qf[0][1], t);
        }

        #pragma unroll
        for (int m = 0; m < 4; ++m) {
            if (m < 3) {                               // QK(m+1) overlaps exp(m)
                #pragma unroll
                for (int ni = 0; ni < 4; ++ni) {
                    f4 t = sinit;
                    t = MFMA(kf[ni][0], qf[m + 1][0], t);
                    sB[ni] = MFMA(kf[ni][1], qf[m + 1][1], t);
                }
            }
            // exp -> (uniform) mask -> row-sum -> pack into dwords D[ni][t']
            unsigned int D[4][2];
            float lm = 0.f;
            #pragma unroll
            for (int ni = 0; ni < 4; ++ni) {
                float p[4];
                #pragma unroll
                for (int reg = 0; reg < 4; ++reg)
                    p[reg] = __builtin_amdgcn_exp2f(sA[ni][reg]);
                if (diag) {
                    #pragma unroll
                    for (int reg = 0; reg < 4; ++reg)
                        if ((ni * 16 + quad * 4 + reg) > (m * 16 + l15)) p[reg] = 0.f;
                }
                lm += (p[0] + p[1]) + (p[2] + p[3]);
                union { float f; unsigned int u; } u0, u1, u2, u3;
                u0.f = p[0]; u1.f = p[1]; u2.f = p[2]; u3.f = p[3];
                // one v_perm_b32 per dword: bytes [u1b3,u1b2,u0b3,u0b2]
                D[ni][0] = __builtin_amdgcn_perm(u1.u, u0.u, 0x07060302u);
                D[ni][1] = __builtin_amdgcn_perm(u3.u, u2.u, 0x07060302u);
            }
            l4[m] += lm;

            // in-register quad-permutation: D -> PV B-frags pb0 (ks=0), pb1 (ks=1)
            union { unsigned int u[4]; bf8 v; } pb0, pb1;
            #pragma unroll
            for (int t = 0; t < 4; ++t) {
                const int srcLane = srcBase[t >> 1];   // ((q&1)*2 + (t>>1))*16 + l15
                unsigned int a0 = (unsigned int)__shfl((int)D[0][t & 1], srcLane);
                unsigned int b0 = (unsigned int)__shfl((int)D[1][t & 1], srcLane);
                pb0.u[t] = hiQuad ? b0 : a0;
                unsigned int a1 = (unsigned int)__shfl((int)D[2][t & 1], srcLane);
                unsigned int b1 = (unsigned int)__shfl((int)D[3][t & 1], srcLane);
                pb1.u[t] = hiQuad ? b1 : a1;
            }

            // O^T += V^T.P^T
            #pragma unroll
            for (int nd = 0; nd < 4; ++nd) o[m][nd] = MFMA(vf[nd][0], pb0.v, o[m][nd]);
            #pragma unroll
            for (int nd = 0; nd < 4; ++nd) o[m][nd] = MFMA(vf[nd][1], pb1.v, o[m][nd]);

            if (m < 3) {
                #pragma unroll
                for (int ni = 0; ni < 4; ++ni) sA[ni] = sB[ni];
            }
        }
    }

    // epilogue: partial row sums + unnormalized O^T -> Opart[query][dim] packed 8B
    const size_t slot = (size_t)h * NITEMS + id;
    #pragma unroll
    for (int m = 0; m < 4; ++m) {
        float l = l4[m];
        l += __shfl_xor(l, 16);
        l += __shfl_xor(l, 32);
        if (quad == 0) Lpart[slot * 64 + m * 16 + l15] = l;
        #pragma unroll
        for (int nd = 0; nd < 4; ++nd) {
            uint2 d;
            d.x = ((unsigned int)f2bf(o[m][nd][1]) << 16) | f2bf(o[m][nd][0]);
            d.y = ((unsigned int)f2bf(o[m][nd][3]) << 16) | f2bf(o[m][nd][2]);
            *(uint2*)&Opart[slot * 4096 + (m * 16 + l15) * 64 + nd * 16 + quad * 4] = d;
        }
    }
}

// ---------------------------------------------------------------------------
// Reduce partials: sum <=8 chunks (uint4 = 8 bf16 at a time), normalize,
// write bf16 Ob[s][768].  One block per (q-tile, head).
// Slot mapping matches the descending-qb enumeration:
//   item id for (chunk cc, qb) = chunk_off(cc) + (63 - qb).
// ---------------------------------------------------------------------------
__global__ __launch_bounds__(256)
void attn_reduce_kernel(const unsigned short* __restrict__ Opart,
                        const float* __restrict__ Lpart,
                        unsigned short* __restrict__ Ob)
{
    const int qb = blockIdx.x, h = blockIdx.y;
    const int nc = qb / CHUNK + 1;
    const int t  = threadIdx.x;
    __shared__ float linv[64];
    if (t < 64) {
        float l = 0.f;
        for (int cc = 0; cc < nc; ++cc)
            l += Lpart[((size_t)h * NITEMS + chunk_off(cc) + 63 - qb) * 64 + t];
        linv[t] = 1.0f / l;
    }
    __syncthreads();
    #pragma unroll
    for (int uu = 0; uu < 2; ++uu) {
        const int u = uu * 256 + t;                   // 0..511
        const int row = u >> 3, ch = (u & 7) * 8;     // 8 cols per unit
        float a[8];
        #pragma unroll
        for (int e = 0; e < 8; ++e) a[e] = 0.f;
        for (int cc = 0; cc < nc; ++cc) {
            const size_t slot = (size_t)h * NITEMS + chunk_off(cc) + 63 - qb;
            uint4 v = *(const uint4*)&Opart[slot * 4096 + row * 64 + ch];
            const unsigned short* pv = (const unsigned short*)&v;
            #pragma unroll
            for (int e = 0; e < 8; ++e) a[e] += bf2f(pv[e]);
        }
        const float il = linv[row];
        ushort4 o[2];
        unsigned short* po = (unsigned short*)o;
        #pragma unroll
        for (int e = 0; e < 8; ++e) po[e] = f2bf(a[e] * il);
        *(uint4*)&Ob[(size_t)(qb * 64 + row) * DM + h * HD + ch] = *(uint4*)o;
    }
}

// ---------------------------------------------------------------------------
// Output projection (MFMA): C = O . wo^T, fp32 out.
// R14: 128x64 tile, 2-wave (128-thread) blocks -> 384 blocks.
// ---------------------------------------------------------------------------
__global__ __launch_bounds__(128)
void proj_mfma_kernel(const unsigned short* __restrict__ Ab,
                      const unsigned short* __restrict__ Wb,
                      float* __restrict__ C)
{
    __shared__ unsigned short smem[(128 + 64) * LDA];    // As(128) | Bs(64)
    unsigned short* As = smem;
    unsigned short* Bs = smem + 128 * LDA;
    const int tid  = threadIdx.x;
    const int wave = tid >> 6, lane = tid & 63;          // 2 waves
    const int l15  = lane & 15, quad = lane >> 4;
    const int mBase = blockIdx.x * 128;
    const int nBase = blockIdx.y * 64;

    f4 acc[4][4];
    #pragma unroll
    for (int mi = 0; mi < 4; ++mi)
        #pragma unroll
        for (int ni = 0; ni < 4; ++ni) acc[mi][ni] = zero4();

    for (int k0 = 0; k0 < DM; k0 += 64) {
        #pragma unroll
        for (int t = 0; t < 8; ++t) {                    // A: 1024 units
            int idx = t * 128 + tid;
            int r = idx >> 3, cc = (idx & 7) * 8;
            *(uint4*)&As[r * LDA + cc] = *(const uint4*)&Ab[(size_t)(mBase + r) * DM + k0 + cc];
        }
        #pragma unroll
        for (int t = 0; t < 4; ++t) {                    // B: 512 units
            int idx = t * 128 + tid;
            int r = idx >> 3, cc = (idx & 7) * 8;
            *(uint4*)&Bs[r * LDA + cc] = *(const uint4*)&Wb[(size_t)(nBase + r) * DM + k0 + cc];
        }
        __syncthreads();
        #pragma unroll
        for (int ks = 0; ks < 2; ++ks) {
            bf8 a[4], b[4];
            #pragma unroll
            for (int mi = 0; mi < 4; ++mi)
                a[mi] = *(const bf8*)&As[(wave * 64 + mi * 16 + l15) * LDA + ks * 32 + quad * 8];
            #pragma unroll
            for (int ni = 0; ni < 4; ++ni)
                b[ni] = *(const bf8*)&Bs[(ni * 16 + l15) * LDA + ks * 32 + quad * 8];
            #pragma unroll
            for (int mi = 0; mi < 4; ++mi)
                #pragma unroll
                for (int ni = 0; ni < 4; ++ni)
                    acc[mi][ni] = MFMA(a[mi], b[ni], acc[mi][ni]);
        }
        __syncthreads();
    }

    #pragma unroll
    for (int mi = 0; mi < 4; ++mi)
        #pragma unroll
        for (int ni = 0; ni < 4; ++ni)
            #pragma unroll
            for (int reg = 0; reg < 4; ++reg) {
                const int m = mBase + wave * 64 + mi * 16 + quad * 4 + reg;
                C[(size_t)m * DM + nBase + ni * 16 + l15] = acc[mi][ni][reg];
            }
}

// ---------------------------------------------------------------------------
extern "C" void kernel_launch(void* const* d_in, const int* in_sizes, int n_in,
                              void* d_out, int out_size, void* d_ws, size_t ws_size,
                              hipStream_t stream) {
    (void)in_sizes; (void)n_in; (void)out_size; (void)ws_size;
    const float* x      = (const float*)d_in[0];
    const float* wq     = (const float*)d_in[1];
    const float* wk     = (const float*)d_in[2];
    const float* wv     = (const float*)d_in[3];
    const float* wo     = (const float*)d_in[4];
    const int*   tokpos = (const int*)d_in[5];
    float* out = (float*)d_out;

    const size_t xN = (size_t)SEQ * DM;             // 3,145,728 shorts
    const size_t wN = (size_t)DM * DM;              //   589,824 shorts

    // persistent region
    float* CS = (float*)d_ws;                       // [4096][32]
    float* SN = CS + 4096 * 32;
    float* Lpart = SN + 4096 * 32;                  // [12][288][64] f32
    unsigned short* wob = (unsigned short*)(Lpart + (size_t)NH * NITEMS * 64);
    unsigned short* Qb  = wob + wN;                 // [h][s][64]
    unsigned short* Kb  = Qb + xN;                  // [h][s][64]
    unsigned short* VbT = Kb + xN;                  // [h][64][4096]
    unsigned short* Ob  = VbT + xN;                 // [s][768]
    // pool region: cast inputs (live until qkv) aliased with Opart (live after)
    unsigned short* pool  = Ob + xN;
    unsigned short* xb    = pool;
    unsigned short* wqb   = xb + xN;
    unsigned short* wkb   = wqb + wN;
    unsigned short* wvb   = wkb + wN;
    unsigned short* Opart = pool;                   // [12][288][64][64] = 28.3 MB

    prep_kernel<<<512 + NCAST, 256, 0, stream>>>(
        x, wq, wk, wv, wo, xb, wqb, wkb, wvb, wob, CS, SN);

    dim3 gQKV(SEQ / 128, NH / 2, 3);
    qkv_mfma_kernel<<<gQKV, 256, 0, stream>>>(xb, wqb, wkb, wvb, tokpos, CS, SN,
                                              Qb, Kb, VbT);

    dim3 gAttn(NITEMS, NH);
    attn_mfma_kernel<<<gAttn, 64, 0, stream>>>(Qb, Kb, VbT, Opart, Lpart);

    dim3 gRed(SEQ / 64, NH);
    attn_reduce_kernel<<<gRed, 256, 0, stream>>>(Opart, Lpart, Ob);

    dim3 gProj(SEQ / 128, DM / 64);
    proj_mfma_kernel<<<gProj, 128, 0, stream>>>(Ob, wob, out);
}